// Round 11
// baseline (271.838 us; speedup 1.0000x reference)
//
#include <hip/hip_runtime.h>
#include <hip/hip_fp16.h>
#include <math.h>

#define DD 160
#define HH 160
#define WW 160
#define NB 2
#define SLICE (HH * WW)        // 25600
#define NV 51200               // NB*160*160 vectors per reduction type
#define Dt 4                   // d's per block
#define NDC 40                 // d-chunks (160/Dt)
#define NHC 10                 // h-chunks
#define HCS 16                 // rows per h-chunk
#define NTHR 320               // 8 groups x 40 float4-lanes
#define NBLK (NB * NDC * NHC)  // 800 blocks; at 4 blocks/CU ALL co-resident
#define NQ (NV / 4)            // 12800 f4-tasks per type

static constexpr float EPS = 1e-12f;
static constexpr float SCALE = -1.0f / 960.0f;  // -(six cos sums)/(160*2*3)

#define ELEM(v, j) ((j) == 0 ? (v).x : ((j) == 1 ? (v).y : ((j) == 2 ? (v).z : (v).w)))

__global__ void zero_kernel(float* out) {
  if (threadIdx.x == 0) out[0] = 0.0f;
}

static __device__ __forceinline__ unsigned pack_h2(float lo, float hi) {
  __half2 h = __halves2half2(__float2half_rn(lo), __float2half_rn(hi));
  return *(unsigned*)&h;
}

// ---------------------------------------------------------------------------
// mainS v4 — occupancy round: R8 body restructured to fit 4 blocks/CU.
//  R10 proved mainS insensitive to write volume (60->36 MB, dur flat) and R9
//  to load timing; the remaining lever is wave count. Two limiters broken:
//   - LDS 50.7 -> 35.0 KB: alongH scratch stored as fp16 (precision mechanism
//     HW-validated in R10: absmax 4.9e-4 vs threshold 1.455e-3). pD is fp32
//     again so only ONE fp16 rounding stage exists.
//   - VGPR 124 -> <=102: aH[24] register array eliminated; r0/r1 row loops
//     merged into one j-loop that dumps 6 alongH values per j to LDS inline
//     (3 packed-half2 dword stores). __launch_bounds__(320,5) => 4 blocks/CU.
//  Tripwires: VGPR<=102, LDS~35KB, WRITE=60.0MB (spill check), absmax<1.5e-3.
// ---------------------------------------------------------------------------
__global__ __launch_bounds__(NTHR, 5) void mainS(const float* __restrict__ f,
                                                 const float* __restrict__ t,
                                                 float* __restrict__ P,
                                                 float* __restrict__ out) {
  __shared__ float sw[HCS * 40 * 7];     // 17920 B: per-(row,lane) alongW partials
  __shared__ unsigned shu[NTHR * 13];    // 16640 B: per-thread 24 fp16 alongH + pad
  __shared__ float red[HCS][6];          //   384 B
  __shared__ float cpad[HCS];            //    64 B   -> total 35008 B
  const int tid = threadIdx.x;
  const int g = tid / 40;               // group 0..7
  const int l = tid % 40;               // float4-lane
  const int w = 4 * l;
  const int wn = (w + 4 < WW) ? (w + 4) : (WW - 1);  // clamp -> gz[3]=0 at w=159
  const int hc = blockIdx.x % NHC;
  const int t2 = blockIdx.x / NHC;
  const int dc = t2 % NDC;
  const int b  = t2 / NDC;
  const int d0 = dc * Dt;
  const int r0 = hc * HCS + g * 2;      // thread's two consecutive rows
  const int r1 = r0 + 1;
  const int r2 = (r1 + 1 < HH) ? (r1 + 1) : (HH - 1);  // clamp -> gy=0 at h=159
  const float* fb = f + (size_t)b * DD * SLICE;
  const float* tb = t + (size_t)b * DD * SLICE;
  float* pH = P;                                  // [NHC][6][NV] fp32
  float* pD = P + (size_t)NHC * 6 * NV;           // [NDC][6][NV] fp32

  // init chained self: slice d0, rows r0,r1 (+ wn scalars)
  float4 S0f = *(const float4*)(fb + (size_t)d0 * SLICE + r0 * WW + w);
  float4 S0t = *(const float4*)(tb + (size_t)d0 * SLICE + r0 * WW + w);
  float4 S1f = *(const float4*)(fb + (size_t)d0 * SLICE + r1 * WW + w);
  float4 S1t = *(const float4*)(tb + (size_t)d0 * SLICE + r1 * WW + w);
  float s0fz = (fb + (size_t)d0 * SLICE + r0 * WW)[wn];
  float s0tz = (tb + (size_t)d0 * SLICE + r0 * WW)[wn];
  float s1fz = (fb + (size_t)d0 * SLICE + r1 * WW)[wn];
  float s1tz = (tb + (size_t)d0 * SLICE + r1 * WW)[wn];

  float aD[48];                         // alongD (gy,gz) persistent accumulators
#pragma unroll
  for (int c = 0; c < 48; ++c) aD[c] = 0.0f;
  float accCos = 0.0f;

#pragma unroll
  for (int p = 0; p < Dt; ++p) {
    const int d = d0 + p;
    const int dn = (d + 1 < DD) ? (d + 1) : d;  // clamp -> gx = 0 at d=159
    const float* fS = fb + (size_t)d * SLICE;
    const float* tS = tb + (size_t)d * SLICE;
    const float* fN = fb + (size_t)dn * SLICE;
    const float* tN = tb + (size_t)dn * SLICE;
    // per-phase loads: 6 f4 + 4 scalars, all independent
    const float4 Hf  = *(const float4*)(fS + r2 * WW + w);
    const float4 Ht  = *(const float4*)(tS + r2 * WW + w);
    const float4 D0f = *(const float4*)(fN + r0 * WW + w);
    const float4 D0t = *(const float4*)(tN + r0 * WW + w);
    const float4 D1f = *(const float4*)(fN + r1 * WW + w);
    const float4 D1t = *(const float4*)(tN + r1 * WW + w);
    const float d0fz = (fN + r0 * WW)[wn], d0tz = (tN + r0 * WW)[wn];
    const float d1fz = (fN + r1 * WW)[wn], d1tz = (tN + r1 * WW)[wn];

    float xd0 = 0, xf0 = 0, xt0 = 0, yd0 = 0, yf0 = 0, yt0 = 0;
    float xd1 = 0, xf1 = 0, xt1 = 0, yd1 = 0, yf1 = 0, yt1 = 0;

    // merged j-loop over both rows; alongH values dumped to LDS per j
    // (no aH register array -> ~24 fewer live VGPRs)
#pragma unroll
    for (int j = 0; j < 4; ++j) {
      float a0, a1, a2, a3, a4, a5;
      {  // row r0: gx = D0-S0, gy = S1-S0, gz = shift(S0)
        const float f0 = ELEM(S0f, j), t0 = ELEM(S0t, j);
        const float gxf = ELEM(D0f, j) - f0, gxt = ELEM(D0t, j) - t0;
        const float gyf = ELEM(S1f, j) - f0, gyt = ELEM(S1t, j) - t0;
        const float fnx = (j < 3) ? ELEM(S0f, j + 1) : s0fz;
        const float tnx = (j < 3) ? ELEM(S0t, j + 1) : s0tz;
        const float gzf = fnx - f0, gzt = tnx - t0;
        xd0 += gxf * gxt; xf0 += gxf * gxf; xt0 += gxt * gxt;
        yd0 += gyf * gyt; yf0 += gyf * gyf; yt0 += gyt * gyt;
        a0 = gxf * gxt; a1 = gxf * gxf; a2 = gxt * gxt;
        a3 = gzf * gzt; a4 = gzf * gzf; a5 = gzt * gzt;
        aD[j * 6 + 0] += gyf * gyt; aD[j * 6 + 1] += gyf * gyf; aD[j * 6 + 2] += gyt * gyt;
        aD[j * 6 + 3] += gzf * gzt; aD[j * 6 + 4] += gzf * gzf; aD[j * 6 + 5] += gzt * gzt;
      }
      {  // row r1: gx = D1-S1, gy = H-S1, gz = shift(S1)
        const float f0 = ELEM(S1f, j), t0 = ELEM(S1t, j);
        const float gxf = ELEM(D1f, j) - f0, gxt = ELEM(D1t, j) - t0;
        const float gyf = ELEM(Hf, j) - f0, gyt = ELEM(Ht, j) - t0;
        const float fnx = (j < 3) ? ELEM(S1f, j + 1) : s1fz;
        const float tnx = (j < 3) ? ELEM(S1t, j + 1) : s1tz;
        const float gzf = fnx - f0, gzt = tnx - t0;
        xd1 += gxf * gxt; xf1 += gxf * gxf; xt1 += gxt * gxt;
        yd1 += gyf * gyt; yf1 += gyf * gyf; yt1 += gyt * gyt;
        a0 += gxf * gxt; a1 += gxf * gxf; a2 += gxt * gxt;
        a3 += gzf * gzt; a4 += gzf * gzf; a5 += gzt * gzt;
        aD[(4 + j) * 6 + 0] += gyf * gyt; aD[(4 + j) * 6 + 1] += gyf * gyf; aD[(4 + j) * 6 + 2] += gyt * gyt;
        aD[(4 + j) * 6 + 3] += gzf * gzt; aD[(4 + j) * 6 + 4] += gzf * gzf; aD[(4 + j) * 6 + 5] += gzt * gzt;
      }
      // inline fp16 dump: halves (a0,a1)(a2,a3)(a4,a5) at dword tid*13 + j*3
      unsigned* su = &shu[tid * 13 + j * 3];
      su[0] = pack_h2(a0, a1);
      su[1] = pack_h2(a2, a3);
      su[2] = pack_h2(a4, a5);
    }
    // alongW partials to LDS (fp32, unchanged)
    {
      float* s = &sw[((g * 2 + 0) * 40 + l) * 7];
      s[0] = xd0; s[1] = xf0; s[2] = xt0; s[3] = yd0; s[4] = yf0; s[5] = yt0;
      float* s1 = &sw[((g * 2 + 1) * 40 + l) * 7];
      s1[0] = xd1; s1[1] = xf1; s1[2] = xt1; s1[3] = yd1; s1[4] = yf1; s1[5] = yt1;
    }
    // register chain: next phase's selves are this phase's d-neighbors
    S0f = D0f; S0t = D0t; S1f = D1f; S1t = D1t;
    s0fz = d0fz; s0tz = d0tz; s1fz = d1fz; s1tz = d1tz;
    // HOISTED pD stores (R8 win, fp32 restored): overlap the final reduce
    if (p == Dt - 1) {
#pragma unroll
      for (int r = 0; r < 2; ++r) {
        const int h = r0 + r;
#pragma unroll
        for (int cc = 0; cc < 6; ++cc) {
          float4 o;
          o.x = aD[(r * 4 + 0) * 6 + cc];
          o.y = aD[(r * 4 + 1) * 6 + cc];
          o.z = aD[(r * 4 + 2) * 6 + cc];
          o.w = aD[(r * 4 + 3) * 6 + cc];
          *(float4*)(pD + ((size_t)(dc * 6 + cc)) * NV + b * SLICE + h * 160 + 4 * l) = o;
        }
      }
    }
    __syncthreads();

    if (tid < 240) {
      // alongH reduce over 8 groups (fp16 LDS reads) + coalesced f4 pH write
      const int cc = tid / 40, ll = tid % 40;
      const __half* hp = (const __half*)shu;
      float v0 = 0, v1 = 0, v2 = 0, v3 = 0;
#pragma unroll
      for (int gg = 0; gg < 8; ++gg) {
        const __half* q = hp + (gg * 40 + ll) * 26;
        v0 += __half2float(q[0 * 6 + cc]);
        v1 += __half2float(q[1 * 6 + cc]);
        v2 += __half2float(q[2 * 6 + cc]);
        v3 += __half2float(q[3 * 6 + cc]);
      }
      const int bd = b * DD + d;
      float4 o; o.x = v0; o.y = v1; o.z = v2; o.w = v3;
      *(float4*)(pH + ((size_t)(hc * 6 + cc)) * NV + bd * 160 + 4 * ll) = o;
    } else {
      // alongW reduce over 40 lanes: 96 tasks on 80 threads
      for (int k = tid - 240; k < HCS * 6; k += 80) {
        const int row = k / 6, c = k % 6;
        float s = 0.0f;
#pragma unroll 8
        for (int ll = 0; ll < 40; ++ll) s += sw[(row * 40 + ll) * 7 + c];
        red[row][c] = s;
      }
    }
    __syncthreads();
    if (tid < HCS) {
      const float cx = red[tid][0] / (fmaxf(sqrtf(red[tid][1]), EPS) * fmaxf(sqrtf(red[tid][2]), EPS));
      const float cy = red[tid][3] / (fmaxf(sqrtf(red[tid][4]), EPS) * fmaxf(sqrtf(red[tid][5]), EPS));
      accCos += cx + cy;
    }
  }

  if (tid < HCS) cpad[tid] = accCos;
  __syncthreads();
  if (tid == 0) {
    float s = 0.0f;
#pragma unroll
    for (int i = 0; i < HCS; ++i) s += cpad[i];
    atomicAdd(out, s * SCALE);
  }
}

// ---------------------------------------------------------------------------
// finalizeW: R8/R9's proven fp32 version, verbatim.
//  - blocks [0,100): alongH types 0,1 — one f4-task per thread, 10-chunk loop.
//  - blocks [100,500): alongD types 2,3 — each f4-task split over 4
//    consecutive threads (10 chunks each), combined by intra-quad __shfl_xor.
// ---------------------------------------------------------------------------
__global__ __launch_bounds__(256) void finalizeW(const float* __restrict__ P,
                                                 float* __restrict__ out) {
  const float* PH = P;
  const float* PD = P + (size_t)NHC * 6 * NV;
  float c = 0.0f;
  if (blockIdx.x < 100) {
    const int u = blockIdx.x * 256 + threadIdx.x;   // [0, 25600)
    const int type = u / NQ;                        // 0: gx-alongH, 1: gz-alongH
    const int vec4 = (u % NQ) * 4;
    float4 dot = {0, 0, 0, 0}, ff = {0, 0, 0, 0}, tt = {0, 0, 0, 0};
    const float* base = PH + (size_t)(type * 3) * NV + vec4;
#pragma unroll
    for (int ch = 0; ch < NHC; ++ch) {
      const float* q = base + (size_t)(ch * 6) * NV;
      const float4 a  = *(const float4*)(q);
      const float4 bb = *(const float4*)(q + (size_t)NV);
      const float4 cv = *(const float4*)(q + 2 * (size_t)NV);
      dot.x += a.x;  dot.y += a.y;  dot.z += a.z;  dot.w += a.w;
      ff.x += bb.x;  ff.y += bb.y;  ff.z += bb.z;  ff.w += bb.w;
      tt.x += cv.x;  tt.y += cv.y;  tt.z += cv.z;  tt.w += cv.w;
    }
    c = dot.x / (fmaxf(sqrtf(ff.x), EPS) * fmaxf(sqrtf(tt.x), EPS))
      + dot.y / (fmaxf(sqrtf(ff.y), EPS) * fmaxf(sqrtf(tt.y), EPS))
      + dot.z / (fmaxf(sqrtf(ff.z), EPS) * fmaxf(sqrtf(tt.z), EPS))
      + dot.w / (fmaxf(sqrtf(ff.w), EPS) * fmaxf(sqrtf(tt.w), EPS));
  } else {
    const int u = (blockIdx.x - 100) * 256 + threadIdx.x;  // [0, 102400)
    const int task = u >> 2, s = u & 3;
    const int type = task / NQ;                     // 0: gy-alongD, 1: gz-alongD
    const int vec4 = (task % NQ) * 4;
    float v[12];
#pragma unroll
    for (int i = 0; i < 12; ++i) v[i] = 0.0f;
    const float* base = PD + (size_t)(type * 3) * NV + vec4;
    for (int ch = s * 10; ch < s * 10 + 10; ++ch) {
      const float* q = base + (size_t)(ch * 6) * NV;
      const float4 a  = *(const float4*)(q);
      const float4 bb = *(const float4*)(q + (size_t)NV);
      const float4 cv = *(const float4*)(q + 2 * (size_t)NV);
      v[0] += a.x;  v[1] += a.y;  v[2]  += a.z;  v[3]  += a.w;
      v[4] += bb.x; v[5] += bb.y; v[6]  += bb.z; v[7]  += bb.w;
      v[8] += cv.x; v[9] += cv.y; v[10] += cv.z; v[11] += cv.w;
    }
#pragma unroll
    for (int i = 0; i < 12; ++i) {
      v[i] += __shfl_xor(v[i], 1);
      v[i] += __shfl_xor(v[i], 2);
    }
    if (s == 0) {
      c = v[0] / (fmaxf(sqrtf(v[4]), EPS) * fmaxf(sqrtf(v[8]),  EPS))
        + v[1] / (fmaxf(sqrtf(v[5]), EPS) * fmaxf(sqrtf(v[9]),  EPS))
        + v[2] / (fmaxf(sqrtf(v[6]), EPS) * fmaxf(sqrtf(v[10]), EPS))
        + v[3] / (fmaxf(sqrtf(v[7]), EPS) * fmaxf(sqrtf(v[11]), EPS));
    }
  }
#pragma unroll
  for (int m = 32; m >= 1; m >>= 1) c += __shfl_xor(c, m);
  __shared__ float part[4];
  if ((threadIdx.x & 63) == 0) part[threadIdx.x >> 6] = c;
  __syncthreads();
  if (threadIdx.x == 0) atomicAdd(out, (part[0] + part[1] + part[2] + part[3]) * SCALE);
}

extern "C" void kernel_launch(void* const* d_in, const int* in_sizes, int n_in,
                              void* d_out, int out_size, void* d_ws, size_t ws_size,
                              hipStream_t stream) {
  const float* fk = (const float*)d_in[0];
  const float* tr = (const float*)d_in[1];
  float* outp = (float*)d_out;
  float* P = (float*)d_ws;   // (NHC+NDC)*6*NV floats = 61.44 MB (proven size)

  hipLaunchKernelGGL(zero_kernel, dim3(1), dim3(64), 0, stream, outp);
  hipLaunchKernelGGL(mainS, dim3(NBLK), dim3(NTHR), 0, stream, fk, tr, P, outp);
  hipLaunchKernelGGL(finalizeW, dim3(500), dim3(256), 0, stream, P, outp);
}

// Round 12
// 153.634 us; speedup vs baseline: 1.7694x; 1.7694x over previous
//
#include <hip/hip_runtime.h>
#include <math.h>

#define DD 160
#define HH 160
#define WW 160
#define NB 2
#define SLICE (HH * WW)        // 25600
#define NV 51200               // NB*160*160 vectors per reduction type
#define Dt 5                   // d's per block -> grid 640 <= 768 capacity (1 residency round)
#define NDC 32                 // d-chunks (160/Dt)
#define NHC 10                 // h-chunks
#define HCS 16                 // rows per h-chunk
#define NTHR 320               // 8 groups x 40 float4-lanes
#define NBLK (NB * NDC * NHC)  // 640 blocks: ALL co-resident at 3 blocks/CU
#define NQ (NV / 4)            // 12800 f4-tasks per type

static constexpr float EPS = 1e-12f;
static constexpr float SCALE = -1.0f / 960.0f;  // -(six cos sums)/(160*2*3)

#define ELEM(v, j) ((j) == 0 ? (v).x : ((j) == 1 ? (v).y : ((j) == 2 ? (v).z : (v).w)))

__global__ void zero_kernel(float* out) {
  if (threadIdx.x == 0) out[0] = 0.0f;
}

// ---------------------------------------------------------------------------
// mainS: EXACT R8 champion body (124 VGPR, 52.5us steady, WRITE==pH+pD,
// absmax 0.0) with ONE parameter change: Dt 4->5 so the grid is 640 blocks,
// all co-resident in a single residency round (vs 800 = 768 + 32-block
// straggler round). Total phase-work identical (800x4 == 640x5).
// R11 lesson applied: natural register demand is ~124; NO launch-bounds
// force (R11's (320,5) produced VGPR=48 + 300 MB of scratch spill).
// Tripwires: VGPR<=128; WRITE must be 51.6 MB exactly (12.3 pH + 39.3 pD).
// ---------------------------------------------------------------------------
__global__ __launch_bounds__(NTHR, 2) void mainS(const float* __restrict__ f,
                                                 const float* __restrict__ t,
                                                 float* __restrict__ P,
                                                 float* __restrict__ out) {
  __shared__ float sw[HCS * 40 * 7];    // per-(row,lane) alongW partials
  __shared__ float sh[8 * 40 * 25];     // per-(group,lane) alongH partials
  __shared__ float red[HCS][6];
  __shared__ float cpad[HCS];
  const int tid = threadIdx.x;
  const int g = tid / 40;               // group 0..7
  const int l = tid % 40;               // float4-lane
  const int w = 4 * l;
  const int wn = (w + 4 < WW) ? (w + 4) : (WW - 1);  // clamp -> gz[3]=0 at w=159
  const int hc = blockIdx.x % NHC;
  const int t2 = blockIdx.x / NHC;
  const int dc = t2 % NDC;
  const int b  = t2 / NDC;
  const int d0 = dc * Dt;
  const int r0 = hc * HCS + g * 2;      // thread's two consecutive rows
  const int r1 = r0 + 1;
  const int r2 = (r1 + 1 < HH) ? (r1 + 1) : (HH - 1);  // clamp -> gy=0 at h=159
  const float* fb = f + (size_t)b * DD * SLICE;
  const float* tb = t + (size_t)b * DD * SLICE;
  float* pH = P;                                  // [NHC][6][NV], vec=(b,d,w)
  float* pD = P + (size_t)NHC * 6 * NV;           // [NDC][6][NV], vec=(b,h,w)

  // init chained self: slice d0, rows r0,r1 (+ wn scalars)
  float4 S0f = *(const float4*)(fb + (size_t)d0 * SLICE + r0 * WW + w);
  float4 S0t = *(const float4*)(tb + (size_t)d0 * SLICE + r0 * WW + w);
  float4 S1f = *(const float4*)(fb + (size_t)d0 * SLICE + r1 * WW + w);
  float4 S1t = *(const float4*)(tb + (size_t)d0 * SLICE + r1 * WW + w);
  float s0fz = (fb + (size_t)d0 * SLICE + r0 * WW)[wn];
  float s0tz = (tb + (size_t)d0 * SLICE + r0 * WW)[wn];
  float s1fz = (fb + (size_t)d0 * SLICE + r1 * WW)[wn];
  float s1tz = (tb + (size_t)d0 * SLICE + r1 * WW)[wn];

  float aD[48];                         // alongD (gy,gz) persistent accumulators
#pragma unroll
  for (int c = 0; c < 48; ++c) aD[c] = 0.0f;
  float accCos = 0.0f;

#pragma unroll
  for (int p = 0; p < Dt; ++p) {
    const int d = d0 + p;
    const int dn = (d + 1 < DD) ? (d + 1) : d;  // clamp -> gx = 0 at d=159
    const float* fS = fb + (size_t)d * SLICE;
    const float* tS = tb + (size_t)d * SLICE;
    const float* fN = fb + (size_t)dn * SLICE;
    const float* tN = tb + (size_t)dn * SLICE;
    // per-phase loads: 6 f4 + 4 scalars, all independent
    const float4 Hf  = *(const float4*)(fS + r2 * WW + w);   // row r2 self (gy for r1)
    const float4 Ht  = *(const float4*)(tS + r2 * WW + w);
    const float4 D0f = *(const float4*)(fN + r0 * WW + w);   // next-d self r0
    const float4 D0t = *(const float4*)(tN + r0 * WW + w);
    const float4 D1f = *(const float4*)(fN + r1 * WW + w);   // next-d self r1
    const float4 D1t = *(const float4*)(tN + r1 * WW + w);
    const float d0fz = (fN + r0 * WW)[wn], d0tz = (tN + r0 * WW)[wn];
    const float d1fz = (fN + r1 * WW)[wn], d1tz = (tN + r1 * WW)[wn];

    float aH[24];
#pragma unroll
    for (int c = 0; c < 24; ++c) aH[c] = 0.0f;

    // ---- row r0: gx = D0-S0, gy = S1-S0, gz = shift(S0) ----
    {
      float xd = 0, xf = 0, xt = 0, yd = 0, yf = 0, yt = 0;
#pragma unroll
      for (int j = 0; j < 4; ++j) {
        const float f0 = ELEM(S0f, j), t0 = ELEM(S0t, j);
        const float gxf = ELEM(D0f, j) - f0, gxt = ELEM(D0t, j) - t0;
        const float gyf = ELEM(S1f, j) - f0, gyt = ELEM(S1t, j) - t0;
        const float fnx = (j < 3) ? ELEM(S0f, j + 1) : s0fz;
        const float tnx = (j < 3) ? ELEM(S0t, j + 1) : s0tz;
        const float gzf = fnx - f0, gzt = tnx - t0;
        xd += gxf * gxt; xf += gxf * gxf; xt += gxt * gxt;
        yd += gyf * gyt; yf += gyf * gyf; yt += gyt * gyt;
        aH[j * 6 + 0] += gxf * gxt; aH[j * 6 + 1] += gxf * gxf; aH[j * 6 + 2] += gxt * gxt;
        aH[j * 6 + 3] += gzf * gzt; aH[j * 6 + 4] += gzf * gzf; aH[j * 6 + 5] += gzt * gzt;
        aD[j * 6 + 0] += gyf * gyt; aD[j * 6 + 1] += gyf * gyf; aD[j * 6 + 2] += gyt * gyt;
        aD[j * 6 + 3] += gzf * gzt; aD[j * 6 + 4] += gzf * gzf; aD[j * 6 + 5] += gzt * gzt;
      }
      float* s = &sw[((g * 2 + 0) * 40 + l) * 7];
      s[0] = xd; s[1] = xf; s[2] = xt; s[3] = yd; s[4] = yf; s[5] = yt;
    }
    // ---- row r1: gx = D1-S1, gy = H-S1, gz = shift(S1) ----
    {
      float xd = 0, xf = 0, xt = 0, yd = 0, yf = 0, yt = 0;
#pragma unroll
      for (int j = 0; j < 4; ++j) {
        const float f0 = ELEM(S1f, j), t0 = ELEM(S1t, j);
        const float gxf = ELEM(D1f, j) - f0, gxt = ELEM(D1t, j) - t0;
        const float gyf = ELEM(Hf, j) - f0, gyt = ELEM(Ht, j) - t0;
        const float fnx = (j < 3) ? ELEM(S1f, j + 1) : s1fz;
        const float tnx = (j < 3) ? ELEM(S1t, j + 1) : s1tz;
        const float gzf = fnx - f0, gzt = tnx - t0;
        xd += gxf * gxt; xf += gxf * gxf; xt += gxt * gxt;
        yd += gyf * gyt; yf += gyf * gyf; yt += gyt * gyt;
        aH[j * 6 + 0] += gxf * gxt; aH[j * 6 + 1] += gxf * gxf; aH[j * 6 + 2] += gxt * gxt;
        aH[j * 6 + 3] += gzf * gzt; aH[j * 6 + 4] += gzf * gzf; aH[j * 6 + 5] += gzt * gzt;
        aD[(4 + j) * 6 + 0] += gyf * gyt; aD[(4 + j) * 6 + 1] += gyf * gyf; aD[(4 + j) * 6 + 2] += gyt * gyt;
        aD[(4 + j) * 6 + 3] += gzf * gzt; aD[(4 + j) * 6 + 4] += gzf * gzf; aD[(4 + j) * 6 + 5] += gzt * gzt;
      }
      float* s = &sw[((g * 2 + 1) * 40 + l) * 7];
      s[0] = xd; s[1] = xf; s[2] = xt; s[3] = yd; s[4] = yf; s[5] = yt;
    }
    // dump alongH partials
    {
      float* s2 = &sh[(g * 40 + l) * 25];
#pragma unroll
      for (int c = 0; c < 24; ++c) s2[c] = aH[c];
    }
    // register chain: next phase's selves are this phase's d-neighbors
    S0f = D0f; S0t = D0t; S1f = D1f; S1t = D1t;
    s0fz = d0fz; s0tz = d0tz; s1fz = d1fz; s1tz = d1tz;

    // HOISTED pD stores (R8 win): aD final in last phase; the write burst
    // overlaps the final reduce instead of draining at kernel exit.
    if (p == Dt - 1) {
#pragma unroll
      for (int r = 0; r < 2; ++r) {
        const int h = r0 + r;
#pragma unroll
        for (int cc = 0; cc < 6; ++cc) {
          float4 o;
          o.x = aD[(r * 4 + 0) * 6 + cc];
          o.y = aD[(r * 4 + 1) * 6 + cc];
          o.z = aD[(r * 4 + 2) * 6 + cc];
          o.w = aD[(r * 4 + 3) * 6 + cc];
          *(float4*)(pD + ((size_t)(dc * 6 + cc)) * NV + b * SLICE + h * 160 + 4 * l) = o;
        }
      }
    }
    __syncthreads();

    if (tid < 240) {
      // alongH reduce over 8 groups + coalesced f4 write to pH
      const int cc = tid / 40, ll = tid % 40;
      float v0 = 0, v1 = 0, v2 = 0, v3 = 0;
#pragma unroll
      for (int gg = 0; gg < 8; ++gg) {
        const float* q = &sh[(gg * 40 + ll) * 25];
        v0 += q[0 * 6 + cc]; v1 += q[1 * 6 + cc]; v2 += q[2 * 6 + cc]; v3 += q[3 * 6 + cc];
      }
      const int bd = b * DD + d;
      float4 o; o.x = v0; o.y = v1; o.z = v2; o.w = v3;
      *(float4*)(pH + ((size_t)(hc * 6 + cc)) * NV + bd * 160 + 4 * ll) = o;
    } else {
      // alongW reduce over 40 lanes: 96 tasks on 80 threads
      for (int k = tid - 240; k < HCS * 6; k += 80) {
        const int row = k / 6, c = k % 6;
        float s = 0.0f;
#pragma unroll 8
        for (int ll = 0; ll < 40; ++ll) s += sw[(row * 40 + ll) * 7 + c];
        red[row][c] = s;
      }
    }
    __syncthreads();
    if (tid < HCS) {
      const float cx = red[tid][0] / (fmaxf(sqrtf(red[tid][1]), EPS) * fmaxf(sqrtf(red[tid][2]), EPS));
      const float cy = red[tid][3] / (fmaxf(sqrtf(red[tid][4]), EPS) * fmaxf(sqrtf(red[tid][5]), EPS));
      accCos += cx + cy;
    }
  }

  if (tid < HCS) cpad[tid] = accCos;
  __syncthreads();
  if (tid == 0) {
    float s = 0.0f;
#pragma unroll
    for (int i = 0; i < HCS; ++i) s += cpad[i];
    atomicAdd(out, s * SCALE);
  }
}

// ---------------------------------------------------------------------------
// finalizeW: R8's proven structure; alongD chunk loop adjusted to NDC=32
// (4-way split -> 8 chunks per thread).
//  - blocks [0,100): alongH types 0,1 — one f4-task per thread, 10-chunk loop.
//  - blocks [100,500): alongD types 2,3 — each f4-task split over 4
//    consecutive threads (8 chunks each), combined by intra-quad __shfl_xor.
// ---------------------------------------------------------------------------
__global__ __launch_bounds__(256) void finalizeW(const float* __restrict__ P,
                                                 float* __restrict__ out) {
  const float* PH = P;
  const float* PD = P + (size_t)NHC * 6 * NV;
  float c = 0.0f;
  if (blockIdx.x < 100) {
    const int u = blockIdx.x * 256 + threadIdx.x;   // [0, 25600)
    const int type = u / NQ;                        // 0: gx-alongH, 1: gz-alongH
    const int vec4 = (u % NQ) * 4;
    float4 dot = {0, 0, 0, 0}, ff = {0, 0, 0, 0}, tt = {0, 0, 0, 0};
    const float* base = PH + (size_t)(type * 3) * NV + vec4;
#pragma unroll
    for (int ch = 0; ch < NHC; ++ch) {
      const float* q = base + (size_t)(ch * 6) * NV;
      const float4 a  = *(const float4*)(q);
      const float4 bb = *(const float4*)(q + (size_t)NV);
      const float4 cv = *(const float4*)(q + 2 * (size_t)NV);
      dot.x += a.x;  dot.y += a.y;  dot.z += a.z;  dot.w += a.w;
      ff.x += bb.x;  ff.y += bb.y;  ff.z += bb.z;  ff.w += bb.w;
      tt.x += cv.x;  tt.y += cv.y;  tt.z += cv.z;  tt.w += cv.w;
    }
    c = dot.x / (fmaxf(sqrtf(ff.x), EPS) * fmaxf(sqrtf(tt.x), EPS))
      + dot.y / (fmaxf(sqrtf(ff.y), EPS) * fmaxf(sqrtf(tt.y), EPS))
      + dot.z / (fmaxf(sqrtf(ff.z), EPS) * fmaxf(sqrtf(tt.z), EPS))
      + dot.w / (fmaxf(sqrtf(ff.w), EPS) * fmaxf(sqrtf(tt.w), EPS));
  } else {
    const int u = (blockIdx.x - 100) * 256 + threadIdx.x;  // [0, 102400)
    const int task = u >> 2, s = u & 3;
    const int type = task / NQ;                     // 0: gy-alongD, 1: gz-alongD
    const int vec4 = (task % NQ) * 4;
    float v[12];
#pragma unroll
    for (int i = 0; i < 12; ++i) v[i] = 0.0f;
    const float* base = PD + (size_t)(type * 3) * NV + vec4;
    for (int ch = s * 8; ch < s * 8 + 8; ++ch) {    // NDC=32: 4 splits x 8 chunks
      const float* q = base + (size_t)(ch * 6) * NV;
      const float4 a  = *(const float4*)(q);
      const float4 bb = *(const float4*)(q + (size_t)NV);
      const float4 cv = *(const float4*)(q + 2 * (size_t)NV);
      v[0] += a.x;  v[1] += a.y;  v[2]  += a.z;  v[3]  += a.w;
      v[4] += bb.x; v[5] += bb.y; v[6]  += bb.z; v[7]  += bb.w;
      v[8] += cv.x; v[9] += cv.y; v[10] += cv.z; v[11] += cv.w;
    }
    // intra-quad combine (splits are consecutive lanes: xor 1,2 stay in-wave)
#pragma unroll
    for (int i = 0; i < 12; ++i) {
      v[i] += __shfl_xor(v[i], 1);
      v[i] += __shfl_xor(v[i], 2);
    }
    if (s == 0) {
      c = v[0] / (fmaxf(sqrtf(v[4]), EPS) * fmaxf(sqrtf(v[8]),  EPS))
        + v[1] / (fmaxf(sqrtf(v[5]), EPS) * fmaxf(sqrtf(v[9]),  EPS))
        + v[2] / (fmaxf(sqrtf(v[6]), EPS) * fmaxf(sqrtf(v[10]), EPS))
        + v[3] / (fmaxf(sqrtf(v[7]), EPS) * fmaxf(sqrtf(v[11]), EPS));
    }
  }
#pragma unroll
  for (int m = 32; m >= 1; m >>= 1) c += __shfl_xor(c, m);
  __shared__ float part[4];
  if ((threadIdx.x & 63) == 0) part[threadIdx.x >> 6] = c;
  __syncthreads();
  if (threadIdx.x == 0) atomicAdd(out, (part[0] + part[1] + part[2] + part[3]) * SCALE);
}

extern "C" void kernel_launch(void* const* d_in, const int* in_sizes, int n_in,
                              void* d_out, int out_size, void* d_ws, size_t ws_size,
                              hipStream_t stream) {
  const float* fk = (const float*)d_in[0];
  const float* tr = (const float*)d_in[1];
  float* outp = (float*)d_out;
  float* P = (float*)d_ws;   // (NHC+NDC)*6*NV floats = 51.6 MB (< proven 61.44 MB)

  hipLaunchKernelGGL(zero_kernel, dim3(1), dim3(64), 0, stream, outp);
  hipLaunchKernelGGL(mainS, dim3(NBLK), dim3(NTHR), 0, stream, fk, tr, P, outp);
  hipLaunchKernelGGL(finalizeW, dim3(500), dim3(256), 0, stream, P, outp);
}

// Round 13
// 139.595 us; speedup vs baseline: 1.9473x; 1.1006x over previous
//
#include <hip/hip_runtime.h>
#include <math.h>

#define DD 160
#define HH 160
#define WW 160
#define NB 2
#define SLICE (HH * WW)        // 25600
#define NV 51200               // NB*160*160 vectors per reduction type
#define Dt 5                   // d's per block -> grid 640: all co-resident (3/CU cap = 768)
#define NDC 32                 // d-chunks (160/Dt)
#define NHC 10                 // h-chunks
#define HCS 16                 // rows per h-chunk
#define NTHR 320               // 8 groups x 40 float4-lanes
#define NBLK (NB * NDC * NHC)  // 640 blocks
#define NQ (NV / 4)            // 12800 f4-tasks per type

static constexpr float EPS = 1e-12f;
static constexpr float SCALE = -1.0f / 960.0f;  // -(six cos sums)/(160*2*3)

#define ELEM(v, j) ((j) == 0 ? (v).x : ((j) == 1 ? (v).y : ((j) == 2 ? (v).z : (v).w)))

__global__ void zero_kernel(float* out) {
  if (threadIdx.x == 0) out[0] = 0.0f;
}

// ---------------------------------------------------------------------------
// mainS: R8 champion per-phase body, Dt=5, with the phase loop ROLLED
// (#pragma unroll 1). R12 proved the Dt=5 FULL UNROLL spills (~38 f/thread,
// WRITE 83.2 vs 51.6 MB); a rolled iteration's live set equals one Dt=4
// unrolled phase (proven 124 VGPR, no spill). This is the clean test of the
// 640-block single-residency-round theory that R12's spill contaminated.
// Tripwires: VGPR<=128, WRITE = 51.6 MB EXACTLY (12.3 pH + 39.3 pD).
// ---------------------------------------------------------------------------
__global__ __launch_bounds__(NTHR, 2) void mainS(const float* __restrict__ f,
                                                 const float* __restrict__ t,
                                                 float* __restrict__ P,
                                                 float* __restrict__ out) {
  __shared__ float sw[HCS * 40 * 7];    // per-(row,lane) alongW partials
  __shared__ float sh[8 * 40 * 25];     // per-(group,lane) alongH partials
  __shared__ float red[HCS][6];
  __shared__ float cpad[HCS];
  const int tid = threadIdx.x;
  const int g = tid / 40;               // group 0..7
  const int l = tid % 40;               // float4-lane
  const int w = 4 * l;
  const int wn = (w + 4 < WW) ? (w + 4) : (WW - 1);  // clamp -> gz[3]=0 at w=159
  const int hc = blockIdx.x % NHC;
  const int t2 = blockIdx.x / NHC;
  const int dc = t2 % NDC;
  const int b  = t2 / NDC;
  const int d0 = dc * Dt;
  const int r0 = hc * HCS + g * 2;      // thread's two consecutive rows
  const int r1 = r0 + 1;
  const int r2 = (r1 + 1 < HH) ? (r1 + 1) : (HH - 1);  // clamp -> gy=0 at h=159
  const float* fb = f + (size_t)b * DD * SLICE;
  const float* tb = t + (size_t)b * DD * SLICE;
  float* pH = P;                                  // [NHC][6][NV], vec=(b,d,w)
  float* pD = P + (size_t)NHC * 6 * NV;           // [NDC][6][NV], vec=(b,h,w)

  // init chained self: slice d0, rows r0,r1 (+ wn scalars)
  float4 S0f = *(const float4*)(fb + (size_t)d0 * SLICE + r0 * WW + w);
  float4 S0t = *(const float4*)(tb + (size_t)d0 * SLICE + r0 * WW + w);
  float4 S1f = *(const float4*)(fb + (size_t)d0 * SLICE + r1 * WW + w);
  float4 S1t = *(const float4*)(tb + (size_t)d0 * SLICE + r1 * WW + w);
  float s0fz = (fb + (size_t)d0 * SLICE + r0 * WW)[wn];
  float s0tz = (tb + (size_t)d0 * SLICE + r0 * WW)[wn];
  float s1fz = (fb + (size_t)d0 * SLICE + r1 * WW)[wn];
  float s1tz = (tb + (size_t)d0 * SLICE + r1 * WW)[wn];

  float aD[48];                         // alongD (gy,gz) persistent accumulators
#pragma unroll
  for (int c = 0; c < 48; ++c) aD[c] = 0.0f;
  float accCos = 0.0f;

#pragma unroll 1
  for (int p = 0; p < Dt; ++p) {
    const int d = d0 + p;
    const int dn = (d + 1 < DD) ? (d + 1) : d;  // clamp -> gx = 0 at d=159
    const float* fS = fb + (size_t)d * SLICE;
    const float* tS = tb + (size_t)d * SLICE;
    const float* fN = fb + (size_t)dn * SLICE;
    const float* tN = tb + (size_t)dn * SLICE;
    // per-phase loads: 6 f4 + 4 scalars, all independent
    const float4 Hf  = *(const float4*)(fS + r2 * WW + w);   // row r2 self (gy for r1)
    const float4 Ht  = *(const float4*)(tS + r2 * WW + w);
    const float4 D0f = *(const float4*)(fN + r0 * WW + w);   // next-d self r0
    const float4 D0t = *(const float4*)(tN + r0 * WW + w);
    const float4 D1f = *(const float4*)(fN + r1 * WW + w);   // next-d self r1
    const float4 D1t = *(const float4*)(tN + r1 * WW + w);
    const float d0fz = (fN + r0 * WW)[wn], d0tz = (tN + r0 * WW)[wn];
    const float d1fz = (fN + r1 * WW)[wn], d1tz = (tN + r1 * WW)[wn];

    float aH[24];
#pragma unroll
    for (int c = 0; c < 24; ++c) aH[c] = 0.0f;

    // ---- row r0: gx = D0-S0, gy = S1-S0, gz = shift(S0) ----
    {
      float xd = 0, xf = 0, xt = 0, yd = 0, yf = 0, yt = 0;
#pragma unroll
      for (int j = 0; j < 4; ++j) {
        const float f0 = ELEM(S0f, j), t0 = ELEM(S0t, j);
        const float gxf = ELEM(D0f, j) - f0, gxt = ELEM(D0t, j) - t0;
        const float gyf = ELEM(S1f, j) - f0, gyt = ELEM(S1t, j) - t0;
        const float fnx = (j < 3) ? ELEM(S0f, j + 1) : s0fz;
        const float tnx = (j < 3) ? ELEM(S0t, j + 1) : s0tz;
        const float gzf = fnx - f0, gzt = tnx - t0;
        xd += gxf * gxt; xf += gxf * gxf; xt += gxt * gxt;
        yd += gyf * gyt; yf += gyf * gyf; yt += gyt * gyt;
        aH[j * 6 + 0] += gxf * gxt; aH[j * 6 + 1] += gxf * gxf; aH[j * 6 + 2] += gxt * gxt;
        aH[j * 6 + 3] += gzf * gzt; aH[j * 6 + 4] += gzf * gzf; aH[j * 6 + 5] += gzt * gzt;
        aD[j * 6 + 0] += gyf * gyt; aD[j * 6 + 1] += gyf * gyf; aD[j * 6 + 2] += gyt * gyt;
        aD[j * 6 + 3] += gzf * gzt; aD[j * 6 + 4] += gzf * gzf; aD[j * 6 + 5] += gzt * gzt;
      }
      float* s = &sw[((g * 2 + 0) * 40 + l) * 7];
      s[0] = xd; s[1] = xf; s[2] = xt; s[3] = yd; s[4] = yf; s[5] = yt;
    }
    // ---- row r1: gx = D1-S1, gy = H-S1, gz = shift(S1) ----
    {
      float xd = 0, xf = 0, xt = 0, yd = 0, yf = 0, yt = 0;
#pragma unroll
      for (int j = 0; j < 4; ++j) {
        const float f0 = ELEM(S1f, j), t0 = ELEM(S1t, j);
        const float gxf = ELEM(D1f, j) - f0, gxt = ELEM(D1t, j) - t0;
        const float gyf = ELEM(Hf, j) - f0, gyt = ELEM(Ht, j) - t0;
        const float fnx = (j < 3) ? ELEM(S1f, j + 1) : s1fz;
        const float tnx = (j < 3) ? ELEM(S1t, j + 1) : s1tz;
        const float gzf = fnx - f0, gzt = tnx - t0;
        xd += gxf * gxt; xf += gxf * gxf; xt += gxt * gxt;
        yd += gyf * gyt; yf += gyf * gyf; yt += gyt * gyt;
        aH[j * 6 + 0] += gxf * gxt; aH[j * 6 + 1] += gxf * gxf; aH[j * 6 + 2] += gxt * gxt;
        aH[j * 6 + 3] += gzf * gzt; aH[j * 6 + 4] += gzf * gzf; aH[j * 6 + 5] += gzt * gzt;
        aD[(4 + j) * 6 + 0] += gyf * gyt; aD[(4 + j) * 6 + 1] += gyf * gyf; aD[(4 + j) * 6 + 2] += gyt * gyt;
        aD[(4 + j) * 6 + 3] += gzf * gzt; aD[(4 + j) * 6 + 4] += gzf * gzf; aD[(4 + j) * 6 + 5] += gzt * gzt;
      }
      float* s = &sw[((g * 2 + 1) * 40 + l) * 7];
      s[0] = xd; s[1] = xf; s[2] = xt; s[3] = yd; s[4] = yf; s[5] = yt;
    }
    // dump alongH partials
    {
      float* s2 = &sh[(g * 40 + l) * 25];
#pragma unroll
      for (int c = 0; c < 24; ++c) s2[c] = aH[c];
    }
    // register chain: next phase's selves are this phase's d-neighbors
    S0f = D0f; S0t = D0t; S1f = D1f; S1t = D1t;
    s0fz = d0fz; s0tz = d0tz; s1fz = d1fz; s1tz = d1tz;

    // HOISTED pD stores (R8 win): aD final in last phase; the write burst
    // overlaps the final reduce instead of draining at kernel exit.
    if (p == Dt - 1) {
#pragma unroll
      for (int r = 0; r < 2; ++r) {
        const int h = r0 + r;
#pragma unroll
        for (int cc = 0; cc < 6; ++cc) {
          float4 o;
          o.x = aD[(r * 4 + 0) * 6 + cc];
          o.y = aD[(r * 4 + 1) * 6 + cc];
          o.z = aD[(r * 4 + 2) * 6 + cc];
          o.w = aD[(r * 4 + 3) * 6 + cc];
          *(float4*)(pD + ((size_t)(dc * 6 + cc)) * NV + b * SLICE + h * 160 + 4 * l) = o;
        }
      }
    }
    __syncthreads();

    if (tid < 240) {
      // alongH reduce over 8 groups + coalesced f4 write to pH
      const int cc = tid / 40, ll = tid % 40;
      float v0 = 0, v1 = 0, v2 = 0, v3 = 0;
#pragma unroll
      for (int gg = 0; gg < 8; ++gg) {
        const float* q = &sh[(gg * 40 + ll) * 25];
        v0 += q[0 * 6 + cc]; v1 += q[1 * 6 + cc]; v2 += q[2 * 6 + cc]; v3 += q[3 * 6 + cc];
      }
      const int bd = b * DD + d;
      float4 o; o.x = v0; o.y = v1; o.z = v2; o.w = v3;
      *(float4*)(pH + ((size_t)(hc * 6 + cc)) * NV + bd * 160 + 4 * ll) = o;
    } else {
      // alongW reduce over 40 lanes: 96 tasks on 80 threads
      for (int k = tid - 240; k < HCS * 6; k += 80) {
        const int row = k / 6, c = k % 6;
        float s = 0.0f;
#pragma unroll 8
        for (int ll = 0; ll < 40; ++ll) s += sw[(row * 40 + ll) * 7 + c];
        red[row][c] = s;
      }
    }
    __syncthreads();
    if (tid < HCS) {
      const float cx = red[tid][0] / (fmaxf(sqrtf(red[tid][1]), EPS) * fmaxf(sqrtf(red[tid][2]), EPS));
      const float cy = red[tid][3] / (fmaxf(sqrtf(red[tid][4]), EPS) * fmaxf(sqrtf(red[tid][5]), EPS));
      accCos += cx + cy;
    }
  }

  if (tid < HCS) cpad[tid] = accCos;
  __syncthreads();
  if (tid == 0) {
    float s = 0.0f;
#pragma unroll
    for (int i = 0; i < HCS; ++i) s += cpad[i];
    atomicAdd(out, s * SCALE);
  }
}

// ---------------------------------------------------------------------------
// finalizeW: unchanged from round 12 (passed, absmax 0.0). NDC=32 split.
//  - blocks [0,100): alongH types 0,1 — one f4-task per thread, 10-chunk loop.
//  - blocks [100,500): alongD types 2,3 — each f4-task split over 4
//    consecutive threads (8 chunks each), combined by intra-quad __shfl_xor.
// ---------------------------------------------------------------------------
__global__ __launch_bounds__(256) void finalizeW(const float* __restrict__ P,
                                                 float* __restrict__ out) {
  const float* PH = P;
  const float* PD = P + (size_t)NHC * 6 * NV;
  float c = 0.0f;
  if (blockIdx.x < 100) {
    const int u = blockIdx.x * 256 + threadIdx.x;   // [0, 25600)
    const int type = u / NQ;                        // 0: gx-alongH, 1: gz-alongH
    const int vec4 = (u % NQ) * 4;
    float4 dot = {0, 0, 0, 0}, ff = {0, 0, 0, 0}, tt = {0, 0, 0, 0};
    const float* base = PH + (size_t)(type * 3) * NV + vec4;
#pragma unroll
    for (int ch = 0; ch < NHC; ++ch) {
      const float* q = base + (size_t)(ch * 6) * NV;
      const float4 a  = *(const float4*)(q);
      const float4 bb = *(const float4*)(q + (size_t)NV);
      const float4 cv = *(const float4*)(q + 2 * (size_t)NV);
      dot.x += a.x;  dot.y += a.y;  dot.z += a.z;  dot.w += a.w;
      ff.x += bb.x;  ff.y += bb.y;  ff.z += bb.z;  ff.w += bb.w;
      tt.x += cv.x;  tt.y += cv.y;  tt.z += cv.z;  tt.w += cv.w;
    }
    c = dot.x / (fmaxf(sqrtf(ff.x), EPS) * fmaxf(sqrtf(tt.x), EPS))
      + dot.y / (fmaxf(sqrtf(ff.y), EPS) * fmaxf(sqrtf(tt.y), EPS))
      + dot.z / (fmaxf(sqrtf(ff.z), EPS) * fmaxf(sqrtf(tt.z), EPS))
      + dot.w / (fmaxf(sqrtf(ff.w), EPS) * fmaxf(sqrtf(tt.w), EPS));
  } else {
    const int u = (blockIdx.x - 100) * 256 + threadIdx.x;  // [0, 102400)
    const int task = u >> 2, s = u & 3;
    const int type = task / NQ;                     // 0: gy-alongD, 1: gz-alongD
    const int vec4 = (task % NQ) * 4;
    float v[12];
#pragma unroll
    for (int i = 0; i < 12; ++i) v[i] = 0.0f;
    const float* base = PD + (size_t)(type * 3) * NV + vec4;
    for (int ch = s * 8; ch < s * 8 + 8; ++ch) {    // NDC=32: 4 splits x 8 chunks
      const float* q = base + (size_t)(ch * 6) * NV;
      const float4 a  = *(const float4*)(q);
      const float4 bb = *(const float4*)(q + (size_t)NV);
      const float4 cv = *(const float4*)(q + 2 * (size_t)NV);
      v[0] += a.x;  v[1] += a.y;  v[2]  += a.z;  v[3]  += a.w;
      v[4] += bb.x; v[5] += bb.y; v[6]  += bb.z; v[7]  += bb.w;
      v[8] += cv.x; v[9] += cv.y; v[10] += cv.z; v[11] += cv.w;
    }
    // intra-quad combine (splits are consecutive lanes: xor 1,2 stay in-wave)
#pragma unroll
    for (int i = 0; i < 12; ++i) {
      v[i] += __shfl_xor(v[i], 1);
      v[i] += __shfl_xor(v[i], 2);
    }
    if (s == 0) {
      c = v[0] / (fmaxf(sqrtf(v[4]), EPS) * fmaxf(sqrtf(v[8]),  EPS))
        + v[1] / (fmaxf(sqrtf(v[5]), EPS) * fmaxf(sqrtf(v[9]),  EPS))
        + v[2] / (fmaxf(sqrtf(v[6]), EPS) * fmaxf(sqrtf(v[10]), EPS))
        + v[3] / (fmaxf(sqrtf(v[7]), EPS) * fmaxf(sqrtf(v[11]), EPS));
    }
  }
#pragma unroll
  for (int m = 32; m >= 1; m >>= 1) c += __shfl_xor(c, m);
  __shared__ float part[4];
  if ((threadIdx.x & 63) == 0) part[threadIdx.x >> 6] = c;
  __syncthreads();
  if (threadIdx.x == 0) atomicAdd(out, (part[0] + part[1] + part[2] + part[3]) * SCALE);
}

extern "C" void kernel_launch(void* const* d_in, const int* in_sizes, int n_in,
                              void* d_out, int out_size, void* d_ws, size_t ws_size,
                              hipStream_t stream) {
  const float* fk = (const float*)d_in[0];
  const float* tr = (const float*)d_in[1];
  float* outp = (float*)d_out;
  float* P = (float*)d_ws;   // (NHC+NDC)*6*NV floats = 51.6 MB (< proven 61.44 MB)

  hipLaunchKernelGGL(zero_kernel, dim3(1), dim3(64), 0, stream, outp);
  hipLaunchKernelGGL(mainS, dim3(NBLK), dim3(NTHR), 0, stream, fk, tr, P, outp);
  hipLaunchKernelGGL(finalizeW, dim3(500), dim3(256), 0, stream, P, outp);
}